// Round 17
// baseline (42.238 us; speedup 1.0000x reference)
//
#include <hip/hip_runtime.h>
#include <math.h>

#define NPTS 4096
#define NB 16
#define RADIUSF 0.07f
#define HF 0.03f
#define EPSF 1e-12f

#define GRIDD 8
#define NCELL 512
#define HCELL 0.125f
#define PPB 72   // partial slots/batch (groups <= 71 proved; slot 71 idle)

// Insert d into sorted-ascending 6-list: L0'=min(L0,d), Lk'=med3(d,L(k-1),Lk).
#define INS6(L, dd) do {                                          \
    const float _d  = (dd);                                       \
    const float _n0 = fminf((L)[0], _d);                          \
    const float _n1 = __builtin_amdgcn_fmed3f(_d, (L)[0], (L)[1]);\
    const float _n2 = __builtin_amdgcn_fmed3f(_d, (L)[1], (L)[2]);\
    const float _n3 = __builtin_amdgcn_fmed3f(_d, (L)[2], (L)[3]);\
    const float _n4 = __builtin_amdgcn_fmed3f(_d, (L)[3], (L)[4]);\
    const float _n5 = __builtin_amdgcn_fmed3f(_d, (L)[4], (L)[5]);\
    (L)[0]=_n0; (L)[1]=_n1; (L)[2]=_n2; (L)[3]=_n3; (L)[4]=_n4; (L)[5]=_n5; \
} while (0)

#define DI(LST, cx, cy, cz) do {                                  \
    const float _ddx = (cx) - mex;                                \
    const float _ddy = (cy) - mey;                                \
    const float _ddz = (cz) - mez;                                \
    INS6(LST, fmaf(_ddz, _ddz, fmaf(_ddy, _ddy, _ddx * _ddx)));   \
} while (0)

__device__ __forceinline__ float loss5(const float* L) {
    float loss = 0.0f;
    #pragma unroll
    for (int i = 1; i < 6; ++i) {               // L[0] == self (exact 0)
        const float d = sqrtf(fmaxf(L[i], EPSF));
        const float t = d / HF;
        loss += (RADIUSF - d) * expf(-t * t);
    }
    return loss;
}

// ---------------------------------------------------------------------------
// Kernel A (r14, proven): per batch, counting-sort into global SoA planes.
// ---------------------------------------------------------------------------
__global__ __launch_bounds__(512) void bin_kernel(
    const float* __restrict__ pred, float* __restrict__ gX,
    float* __restrict__ gY, float* __restrict__ gZ,
    int* __restrict__ cellStart)
{
    __shared__ int h[NCELL];
    __shared__ int cur[NCELL];
    __shared__ int start[NCELL];
    __shared__ int wsum[8], wpre[8];

    const int b = blockIdx.x, t = threadIdx.x;
    const int lane = t & 63, w = t >> 6;
    h[t] = 0; cur[t] = 0;
    __syncthreads();

    const float* pb = pred + (size_t)b * NPTS * 3;
    int cid[8];
    #pragma unroll
    for (int k = 0; k < 8; ++k) {
        const int p = k * 512 + t;
        const float x = pb[3 * p], y = pb[3 * p + 1], z = pb[3 * p + 2];
        const int ix = min(GRIDD - 1, max(0, (int)(x * (float)GRIDD)));
        const int iy = min(GRIDD - 1, max(0, (int)(y * (float)GRIDD)));
        const int iz = min(GRIDD - 1, max(0, (int)(z * (float)GRIDD)));
        cid[k] = (ix << 6) + (iy << 3) + iz;
        atomicAdd(&h[cid[k]], 1);
    }
    __syncthreads();

    int v = h[t];
    #pragma unroll
    for (int off = 1; off < 64; off <<= 1) {
        const int u = __shfl_up(v, off, 64);
        if (lane >= off) v += u;
    }
    if (lane == 63) wsum[w] = v;
    __syncthreads();
    if (t < 8) {
        int s = 0;
        for (int i = 0; i < t; ++i) s += wsum[i];
        wpre[t] = s;
    }
    __syncthreads();
    start[t] = v + wpre[w] - h[t];               // exclusive start
    __syncthreads();

    #pragma unroll
    for (int k = 0; k < 8; ++k) {
        const int p = k * 512 + t;
        const float x = pb[3 * p], y = pb[3 * p + 1], z = pb[3 * p + 2];
        const int dst = start[cid[k]] + atomicAdd(&cur[cid[k]], 1);
        gX[(size_t)b * NPTS + dst] = x;
        gY[(size_t)b * NPTS + dst] = y;
        gZ[(size_t)b * NPTS + dst] = z;
    }

    cellStart[b * (NCELL + 1) + t] = start[t];
    if (t == 0) cellStart[b * (NCELL + 1) + NCELL] = NPTS;
}

// ---------------------------------------------------------------------------
// Kernel B: 1024-thr block = 2 teams x 8 waves; team = one slab-aligned
// 64-query group. Full batch SoA planes staged once into LDS (coalesced,
// no atomics -> no bank conflicts). Team streams its y-bbox window
// (3 x-slabs x y-band, 2-3 contiguous segments) with aligned ds_read_b128
// broadcasts, 8-wave split, A/B lists, 3-round tree merge. Coverage proof;
// flagged queries exact-scanned from LDS. 8 waves/SIMD occupancy.
// ---------------------------------------------------------------------------
__global__ __launch_bounds__(1024, 8) void search_kernel(
    const float* __restrict__ gX, const float* __restrict__ gY,
    const float* __restrict__ gZ, const int* __restrict__ cellStart,
    float* __restrict__ partial)
{
    __shared__ __align__(16) float sx[NPTS];
    __shared__ __align__(16) float sy[NPTS];
    __shared__ __align__(16) float sz[NPTS];       // 48 KB
    __shared__ unsigned short cs[NCELL + 2];       // 1 KB
    __shared__ float Lm[2][4][64][6];              // 12 KB

    const int bid  = blockIdx.x;
    const int b    = bid / 36;                     // batch
    const int pair = bid % 36;                     // group pair
    const int t = threadIdx.x, lane = t & 63;
    const int w = t >> 6, team = w >> 3, tw = w & 7;
    const int g = pair * 2 + team;                 // group id (0..71)

    // ---- Stage planes + cell table (coalesced, conflict-free).
    const float* gXb = gX + (size_t)b * NPTS;
    const float* gYb = gY + (size_t)b * NPTS;
    const float* gZb = gZ + (size_t)b * NPTS;
    #pragma unroll
    for (int i = 0; i < NPTS / 1024; ++i) {
        sx[i * 1024 + t] = gXb[i * 1024 + t];
        sy[i * 1024 + t] = gYb[i * 1024 + t];
        sz[i * 1024 + t] = gZb[i * 1024 + t];
    }
    if (t < NCELL + 1) cs[t] = (unsigned short)cellStart[b * (NCELL + 1) + t];
    __syncthreads();

    // ---- Group assignment (uniform per team; groups/slab = ceil(cnt/64)).
    int Xsel = -1, ksel = 0, accg = 0;
    #pragma unroll
    for (int Xs = 0; Xs < 8; ++Xs) {
        const int c0 = cs[Xs << 6];
        const int c1 = cs[(Xs + 1) << 6];
        const int ng = (c1 - c0 + 63) >> 6;
        if (g >= accg && g < accg + ng) { Xsel = Xs; ksel = g - accg; }
        accg += ng;
    }
    const bool teamIdle = (Xsel < 0);
    if (teamIdle) { Xsel = 0; ksel = 0; }          // safe coords, inactive

    const int slab0   = cs[Xsel << 6];
    const int slabEnd = cs[(Xsel + 1) << 6];
    const int qs = slab0 + 64 * ksel;
    const int qe = teamIdle ? qs : min(qs + 64, slabEnd);

    const bool active = (qs + lane) < qe;          // same mask in all 8 waves
    const int  qi = active ? (qs + lane) : qs;
    const float mex = sx[qi], mey = sy[qi], mez = sz[qi];

    // Group y-bbox over ACTIVE lanes (identical across the team's waves).
    const int iyq = min(7, max(0, (int)(mey * 8.0f)));
    int ymn = active ? iyq : 8, ymx = active ? iyq : -1;
    #pragma unroll
    for (int m = 1; m < 64; m <<= 1) {
        ymn = min(ymn, __shfl_xor(ymn, m, 64));
        ymx = max(ymx, __shfl_xor(ymx, m, 64));
    }
    const int ylo = max(ymn - 1, 0), yhi = min(ymx + 1, 7);
    const int xlo = max(Xsel - 1, 0), xhi = min(Xsel + 1, 7);

    float A6[6], B6[6];
    #pragma unroll
    for (int i = 0; i < 6; ++i) { A6[i] = 1e30f; B6[i] = 1e30f; }

    // ---- Stream 2-3 contiguous segments (broadcast b128 reads, 8-wave split).
    if (!teamIdle) {
        for (int Xs = xlo; Xs <= xhi; ++Xs) {
            const int seg0 = cs[(Xs << 6) + (ylo << 3)];
            const int seg1 = cs[(Xs << 6) + ((yhi + 1) << 3)];  // + not | (carry)
            const int bodyS = (seg0 + 3) & ~3;
            const int bodyE = max(bodyS, seg1 & ~3);
            if (tw == 0) {                         // head (<=3), in-bounds
                const int he = min(bodyS, seg1);
                for (int s = seg0; s < he; ++s) DI(A6, sx[s], sy[s], sz[s]);
            }
            if (tw == 7) {                         // tail (<=3), in-bounds
                for (int s = bodyE; s < seg1; ++s) DI(A6, sx[s], sy[s], sz[s]);
            }
            int s = bodyS + 8 * tw;                // aligned 8-cand chunks
            for (; s + 8 <= bodyE; s += 64) {
                const float4 x0 = *(const float4*)(sx + s);
                const float4 x1 = *(const float4*)(sx + s + 4);
                const float4 y0 = *(const float4*)(sy + s);
                const float4 y1 = *(const float4*)(sy + s + 4);
                const float4 z0 = *(const float4*)(sz + s);
                const float4 z1 = *(const float4*)(sz + s + 4);
                DI(A6, x0.x, y0.x, z0.x);  DI(B6, x0.y, y0.y, z0.y);
                DI(A6, x0.z, y0.z, z0.z);  DI(B6, x0.w, y0.w, z0.w);
                DI(A6, x1.x, y1.x, z1.x);  DI(B6, x1.y, y1.y, z1.y);
                DI(A6, x1.z, y1.z, z1.z);  DI(B6, x1.w, y1.w, z1.w);
            }
            const int e = min(s + 8, bodyE);       // this wave's partial chunk
            for (; s < e; ++s) DI(A6, sx[s], sy[s], sz[s]);
        }
    }
    #pragma unroll
    for (int i = 0; i < 6; ++i) INS6(A6, B6[i]);

    // ---- Exact 8-wave tree merge per team (3 rounds, block barriers).
    if (tw >= 4) {
        #pragma unroll
        for (int i = 0; i < 6; ++i) Lm[team][tw - 4][lane][i] = A6[i];
    }
    __syncthreads();
    if (tw < 4) {
        #pragma unroll
        for (int i = 0; i < 6; ++i) INS6(A6, Lm[team][tw][lane][i]);
    }
    __syncthreads();
    if (tw == 2 || tw == 3) {
        #pragma unroll
        for (int i = 0; i < 6; ++i) Lm[team][tw - 2][lane][i] = A6[i];
    }
    __syncthreads();
    if (tw < 2) {
        #pragma unroll
        for (int i = 0; i < 6; ++i) INS6(A6, Lm[team][tw][lane][i]);
    }
    __syncthreads();
    if (tw == 1) {
        #pragma unroll
        for (int i = 0; i < 6; ++i) Lm[team][0][lane][i] = A6[i];
    }
    __syncthreads();

    if (tw == 0) {
        #pragma unroll
        for (int i = 0; i < 6; ++i) INS6(A6, Lm[team][0][lane][i]);

        // Coverage: non-boundary x,y window faces (z fully covered).
        float cov = 1e30f;
        if (xlo > 0) cov = fminf(cov, mex - (float)xlo * HCELL);
        if (xhi < 7) cov = fminf(cov, (float)(xhi + 1) * HCELL - mex);
        if (ylo > 0) cov = fminf(cov, mey - (float)ylo * HCELL);
        if (yhi < 7) cov = fminf(cov, (float)(yhi + 1) * HCELL - mey);

        const bool ok = active && (A6[5] <= cov * cov);
        float loss = ok ? loss5(A6) : 0.0f;

        // Exact full-batch LDS scan for flagged queries (rare: corners).
        unsigned long long flagged = __ballot(active && !ok);
        while (flagged) {
            const int src = __ffsll(flagged) - 1;
            flagged &= flagged - 1;
            const float fx = __shfl(mex, src, 64);
            const float fy = __shfl(mey, src, 64);
            const float fz = __shfl(mez, src, 64);
            float F[6];
            #pragma unroll
            for (int i = 0; i < 6; ++i) F[i] = 1e30f;
            for (int p2 = lane; p2 < NPTS; p2 += 64) {   // conflict-free b32
                const float ddx = sx[p2] - fx;
                const float ddy = sy[p2] - fy;
                const float ddz = sz[p2] - fz;
                INS6(F, fmaf(ddz, ddz, fmaf(ddy, ddy, ddx * ddx)));
            }
            #pragma unroll
            for (int off = 32; off >= 1; off >>= 1) {    // tree -> lane 0
                float R[6];
                #pragma unroll
                for (int i = 0; i < 6; ++i) R[i] = __shfl_down(F[i], off, 64);
                #pragma unroll
                for (int i = 0; i < 6; ++i) INS6(F, R[i]);
            }
            const float fl = __shfl((lane == 0) ? loss5(F) : 0.0f, 0, 64);
            if (lane == src) loss = fl;
        }

        #pragma unroll
        for (int off = 32; off > 0; off >>= 1)
            loss += __shfl_down(loss, off, 64);
        if (lane == 0) partial[b * PPB + g] = loss;
    }
}

// NB*PPB = 1152 partials: thread t -> batch t>>4, strided 16-lane reduce.
__global__ void final_kernel(const float* __restrict__ partial,
                             float* __restrict__ out)
{
    const int t = threadIdx.x;
    const int bb = t >> 4, j = t & 15;
    float s = 0.0f;
    for (int i = j; i < PPB; i += 16) s += partial[bb * PPB + i];
    #pragma unroll
    for (int off = 8; off > 0; off >>= 1)
        s += __shfl_down(s, off, 16);
    if (j == 0) out[bb] = s * (1.0f / ((float)NPTS * 5.0f));
}

// ---------------------------------------------------------------------------
// Emergency path (tiny workspace): monolithic brute force.
// ---------------------------------------------------------------------------
__global__ __launch_bounds__(256) void mono_kernel(
    const float* __restrict__ pred, float* __restrict__ partial)
{
    __shared__ __align__(16) float sxm[NPTS];
    __shared__ __align__(16) float sym[NPTS];
    __shared__ __align__(16) float szm[NPTS];
    __shared__ float red[4];

    const int b     = blockIdx.x >> 4;
    const int chunk = blockIdx.x & 15;
    const float* pb = pred + (size_t)b * NPTS * 3;

    for (int p = threadIdx.x; p < NPTS; p += 256) {
        sxm[p] = pb[3 * p + 0]; sym[p] = pb[3 * p + 1]; szm[p] = pb[3 * p + 2];
    }
    __syncthreads();

    const int n = chunk * 256 + threadIdx.x;
    const float mex = pb[3 * n], mey = pb[3 * n + 1], mez = pb[3 * n + 2];

    float A[6], B[6];
    #pragma unroll
    for (int i = 0; i < 6; ++i) { A[i] = 1e30f; B[i] = 1e30f; }

    const float4* X4 = (const float4*)sxm;
    const float4* Y4 = (const float4*)sym;
    const float4* Z4 = (const float4*)szm;

    #pragma unroll 2
    for (int gI = 0; gI < NPTS / 4; ++gI) {
        const float4 X = X4[gI], Y = Y4[gI], Z = Z4[gI];
        DI(A, X.x, Y.x, Z.x);
        DI(B, X.y, Y.y, Z.y);
        DI(A, X.z, Y.z, Z.z);
        DI(B, X.w, Y.w, Z.w);
    }
    #pragma unroll
    for (int i = 0; i < 6; ++i) INS6(A, B[i]);

    float loss = loss5(A);
    #pragma unroll
    for (int off = 32; off > 0; off >>= 1)
        loss += __shfl_down(loss, off, 64);
    const int wave = threadIdx.x >> 6, lane = threadIdx.x & 63;
    if (lane == 0) red[wave] = loss;
    __syncthreads();
    if (threadIdx.x == 0) {
        float s = 0.0f;
        #pragma unroll
        for (int w = 0; w < 4; ++w) s += red[w];
        partial[blockIdx.x] = s;
    }
}

__global__ void mono_final_kernel(const float* __restrict__ partial,
                                  float* __restrict__ out)
{
    const int b = threadIdx.x;
    if (b < NB) {
        float s = 0.0f;
        #pragma unroll
        for (int i = 0; i < 16; ++i) s += partial[b * 16 + i];
        out[b] = s * (1.0f / ((float)NPTS * 5.0f));
    }
}

extern "C" void kernel_launch(void* const* d_in, const int* in_sizes, int n_in,
                              void* d_out, int out_size, void* d_ws, size_t ws_size,
                              hipStream_t stream)
{
    const float* pred = (const float*)d_in[0];
    float* out        = (float*)d_out;
    char* ws          = (char*)d_ws;

    const size_t planeB  = (size_t)NB * NPTS * sizeof(float);  // 256 KB
    const size_t off_gX  = 0;
    const size_t off_gY  = off_gX + planeB;
    const size_t off_gZ  = off_gY + planeB;
    const size_t off_cs  = off_gZ + planeB;
    const size_t off_par = off_cs + (size_t)NB * (NCELL + 1) * sizeof(int);
    const size_t need    = off_par + (size_t)NB * PPB * sizeof(float);

    if (ws_size >= need) {
        float* gXp     = (float*)(ws + off_gX);
        float* gYp     = (float*)(ws + off_gY);
        float* gZp     = (float*)(ws + off_gZ);
        int*   cellS   = (int*)(ws + off_cs);
        float* partial = (float*)(ws + off_par);

        bin_kernel<<<dim3(NB), dim3(512), 0, stream>>>(pred, gXp, gYp, gZp, cellS);
        search_kernel<<<dim3(NB * 36), dim3(1024), 0, stream>>>(
            gXp, gYp, gZp, cellS, partial);
        final_kernel<<<dim3(1), dim3(256), 0, stream>>>(partial, out);
    } else {
        float* partial = (float*)d_ws;                 // 256 floats
        mono_kernel<<<dim3(256), dim3(256), 0, stream>>>(pred, partial);
        mono_final_kernel<<<dim3(1), dim3(64), 0, stream>>>(partial, out);
    }
}